// Round 10
// baseline (214.867 us; speedup 1.0000x reference)
//
#include <hip/hip_runtime.h>
#include <math.h>

// Clockwork RNN, B=512 T=192 DX=32 DH1=256 DH2=512 DY=4
// R9: latency hiding via TWO independent blocks per CU + halved epilogue.
//  - 512 blocks x (4 batch rows, one y) x 512 thr -> 2 blocks/CU, 4 waves/SIMD
//    with INDEPENDENT barriers (block A computes while block B waits).
//    B-fragment rows 4-way duplicated (rb = r&3) -> more MFMA but less LDS.
//  - lane-half epilogue split: r<8 lanes finish tile0, r>=8 finish tile1
//    (they were computing identical duplicates) -> one 4-wide tanh+pack chain
//    serves both tiles; single ds_write_b64; carry folded via early read+select.
//  - h fp16 single array (R7), single fp16 W registers (R8), k-split dual
//    accumulator chains, 1 barrier/step, x register prefetch, W fragments
//    FULLY UNROLLED (R2 scratch-demotion lesson).

#define TT    192
#define DXX   32
#define DH1   256
#define DH2   512
#define NY    4
#define ROWS4 4
#define PADK  264   // row stride in fp16 elems (528B)

typedef _Float16 f16x8 __attribute__((ext_vector_type(8)));
typedef __attribute__((ext_vector_type(4))) float f32x4;
typedef __attribute__((ext_vector_type(2))) int   i32x2;
typedef __attribute__((ext_vector_type(4))) int   i32x4;

template<int N> struct IC { static constexpr int v = N; };

__device__ __forceinline__ unsigned pkrtz(float a, float b) {
    unsigned d;
    asm("v_cvt_pkrtz_f16_f32 %0, %1, %2" : "=v"(d) : "v"(a), "v"(b));
    return d;   // lo16 = f16(a), hi16 = f16(b), RTZ (x input only)
}
__device__ __forceinline__ unsigned short f16bits(_Float16 h) {
    union { _Float16 f; unsigned short u; } c; c.f = h; return c.u;
}
__device__ __forceinline__ float fast_tanh(float v) {
    float t = __builtin_amdgcn_exp2f(v * 2.885390081777927f);
    return fmaf(-2.f, __builtin_amdgcn_rcpf(t + 1.f), 1.f);
}

__global__ __launch_bounds__(512, 4) void cwrnn_mfma9(
    const float* __restrict__ x,     // [B,T,DX]
    const float* __restrict__ w_x,   // [DY,DX,DH1]
    const float* __restrict__ w_h,   // [DY,DH1,DH1]
    const float* __restrict__ bias,  // [DY,DH1]
    const float* __restrict__ W1,    // [DY,DH1,DH2]
    const float* __restrict__ b1,    // [DY,DH2]
    const float* __restrict__ W2,    // [DY,DH2]
    const float* __restrict__ b2,    // [DY]
    float* __restrict__ out)         // [B,DY]
{
    __shared__ _Float16 hb[2][ROWS4 * PADK];   // h fp16, [buf][row][k]
    __shared__ float red[8][ROWS4];
    __shared__ float scratch[DXX * DH1];       // 32KB staging; reused as hT

    const int t    = threadIdx.x;
    const int lane = t & 63;
    const int w    = t >> 6;        // wave 0..7; tiles {w, 8+w}
    const int r    = lane & 15;
    const int rb   = r & 3;         // batch row (4-way duplicated)
    const int q    = lane >> 4;
    const int y    = blockIdx.x & 3;
    const int b0   = (blockIdx.x >> 2) * ROWS4;

    const float* wx_g = w_x + (size_t)y * DXX * DH1;
    const float* wh_g = w_h + (size_t)y * DH1 * DH1;

    for (int i = t; i < ROWS4 * PADK; i += 512) hb[0][i] = (_Float16)0.f;

    // ---- w_x fragments: wave w -> tiles {w, 8+w}; single fp16 ----
    f16x8 wxf[2];
    for (int i = t * 4; i < DXX * DH1; i += 2048)
        *(f32x4*)&scratch[i] = *(const f32x4*)&wx_g[i];
    __syncthreads();
    #pragma unroll
    for (int m = 0; m < 2; ++m) {
        f16x8 vh;
        #pragma unroll
        for (int jj = 0; jj < 8; ++jj)
            vh[jj] = (_Float16)scratch[(q * 8 + jj) * DH1 + ((m * 8 + w) << 4) + r];
        wxf[m] = vh;
    }
    __syncthreads();

    // ---- w_h fragments: 8 ktiles x 2 mtiles, single fp16. FULLY UNROLLED
    // (runtime index -> scratch demotion; R2 lesson). ----
    f16x8 whf[8][2];
    #pragma unroll
    for (int kt = 0; kt < 8; ++kt) {
        for (int i = t * 4; i < 32 * DH1; i += 2048)
            *(f32x4*)&scratch[i] = *(const f32x4*)&wh_g[kt * 32 * DH1 + i];
        __syncthreads();
        #pragma unroll
        for (int m = 0; m < 2; ++m) {
            f16x8 vh;
            #pragma unroll
            for (int jj = 0; jj < 8; ++jj)
                vh[jj] = (_Float16)scratch[(q * 8 + jj) * DH1 + ((m * 8 + w) << 4) + r];
            whf[kt][m] = vh;
        }
        __syncthreads();
    }

    f32x4 bias4[2];
    #pragma unroll
    for (int m = 0; m < 2; ++m)
        #pragma unroll
        for (int rr = 0; rr < 4; ++rr)
            bias4[m][rr] = bias[y * DH1 + ((m * 8 + w) << 4) + q * 4 + rr];

    // ---- per-lane LDS pointers ----
    const _Float16* hrd[2] = { &hb[0][rb * PADK] + q * 8,
                               &hb[1][rb * PADK] + q * 8 };
    // lane-half split write/carry address: r<8 -> tile w, r>=8 -> tile 8+w
    const int tile_off = ((r < 8) ? w : 8 + w) << 4;
    _Float16* hws[2] = { &hb[0][rb * PADK + tile_off + q * 4],
                         &hb[1][rb * PADK + tile_off + q * 4] };
    const bool wlane = ((r & 7) < 4);   // unique-writer lanes

    const float* xrow = x + (size_t)(b0 + rb) * TT * DXX + q * 8;
    f32x4 cxa = *(const f32x4*)&xrow[0];
    f32x4 cxb = *(const f32x4*)&xrow[4];

    // ---- one recurrence step ----
    auto body = [&](int j, auto SC, int cur) {
        constexpr int S  = SC.v;                       // 0:NC=128 1:192 2:256
        constexpr int NF = (S == 0) ? 16 : (S == 1) ? 24 : 32;
        const bool m1act = (S == 2) || (S == 1 && w < 4);

        // prefetch next step's x
        const int jn = (j + 1 < TT) ? j + 1 : j;
        const f32x4 pxa = *(const f32x4*)&xrow[jn * DXX];
        const f32x4 pxb = *(const f32x4*)&xrow[jn * DXX + 4];

        // clockwork carry pre-read (old tile1 value for r>=8 lanes)
        i32x2 old1;
        if (!m1act) old1 = *(const i32x2*)(hws[cur]);

        // x B-fragment, fp16 (quad-uniform feature mask)
        f16x8 xf;
        if (q * 8 < NF) {
            union { i32x4 i; f16x8 h; } ux;
            ux.i = (i32x4){ (int)pkrtz(cxa[0], cxa[1]), (int)pkrtz(cxa[2], cxa[3]),
                            (int)pkrtz(cxb[0], cxb[1]), (int)pkrtz(cxb[2], cxb[3]) };
            xf = ux.h;
        } else {
            xf = (f16x8)(_Float16)0.f;
        }

        const _Float16* hp = hrd[cur];

        // k-split accumulators: kt0-3 -> a, kt4-7 + x -> b (2 indep chains)
        f32x4 a0a = bias4[0], a0b = {0,0,0,0};
        f32x4 a1a = bias4[1], a1b = {0,0,0,0};

        #pragma unroll
        for (int kt = 0; kt < 4; ++kt) {
            const f16x8 hv0 = *(const f16x8*)(hp + kt * 32);
            const f16x8 hv1 = *(const f16x8*)(hp + (kt + 4) * 32);
            a0a = __builtin_amdgcn_mfma_f32_16x16x32_f16(whf[kt][0], hv0, a0a, 0, 0, 0);
            a0b = __builtin_amdgcn_mfma_f32_16x16x32_f16(whf[kt + 4][0], hv1, a0b, 0, 0, 0);
            if (m1act) {
                a1a = __builtin_amdgcn_mfma_f32_16x16x32_f16(whf[kt][1], hv0, a1a, 0, 0, 0);
                a1b = __builtin_amdgcn_mfma_f32_16x16x32_f16(whf[kt + 4][1], hv1, a1b, 0, 0, 0);
            }
        }
        a0b = __builtin_amdgcn_mfma_f32_16x16x32_f16(wxf[0], xf, a0b, 0, 0, 0);
        if (m1act)
            a1b = __builtin_amdgcn_mfma_f32_16x16x32_f16(wxf[1], xf, a1b, 0, 0, 0);

        // ---- epilogue: lane-half tile select -> ONE tanh/pack pipeline ----
        {
            const f32x4 s0 = a0a + a0b;
            f32x4 sel;
            if (m1act) {
                const f32x4 s1 = a1a + a1b;
                sel[0] = (r < 8) ? s0[0] : s1[0];
                sel[1] = (r < 8) ? s0[1] : s1[1];
                sel[2] = (r < 8) ? s0[2] : s1[2];
                sel[3] = (r < 8) ? s0[3] : s1[3];
            } else {
                sel = s0;   // r>=8 lanes produce garbage; overridden by old1
            }
            const unsigned short h0 = f16bits((_Float16)fast_tanh(sel[0]));
            const unsigned short h1 = f16bits((_Float16)fast_tanh(sel[1]));
            const unsigned short h2 = f16bits((_Float16)fast_tanh(sel[2]));
            const unsigned short h3 = f16bits((_Float16)fast_tanh(sel[3]));
            i32x2 wv = (i32x2){ (int)(h0 | ((unsigned)h1 << 16)),
                                (int)(h2 | ((unsigned)h3 << 16)) };
            if (!m1act && r >= 8) wv = old1;   // clockwork carry
            if (wlane) *(i32x2*)(hws[cur ^ 1]) = wv;
        }
        __syncthreads();
        cxa = pxa; cxb = pxb;
    };

    // ---- main loop ----
    for (int j = 0; j < TT; j += 4) {
        body(j + 0, IC<0>{}, 0);   // jp odd           -> NC=128
        body(j + 1, IC<1>{}, 1);   // jp%2==0, %4!=0   -> NC=192
        body(j + 2, IC<0>{}, 0);   // jp odd           -> NC=128
        body(j + 3, IC<2>{}, 1);   // jp%4==0          -> NC=256
    }
    // final h in buffer 0

    // ---- rebuild h fp32, transposed [k][row] ----
    float* hT = scratch;
    for (int i = t; i < DH1 * ROWS4; i += 512) {
        const int row = i & 3, k = i >> 2;
        hT[k * ROWS4 + row] = (float)hb[0][row * PADK + k];
    }
    __syncthreads();

    // ---- head: hid = relu(h @ W1 + b1); y = hid @ W2 + b2 ----
    const float* W1_g = W1 + (size_t)y * DH1 * DH2;
    float a0[4];
    #pragma unroll
    for (int m = 0; m < 4; ++m) a0[m] = 0.f;
    for (int k = 0; k < DH1; ++k) {
        const float wv = W1_g[(size_t)k * DH2 + t];
        const f32x4 hA = *(const f32x4*)&hT[k * ROWS4];
        a0[0] += hA[0] * wv; a0[1] += hA[1] * wv;
        a0[2] += hA[2] * wv; a0[3] += hA[3] * wv;
    }
    {
        const float b1v = b1[y * DH2 + t];
        const float w2v = W2[y * DH2 + t];
        float p[4];
        #pragma unroll
        for (int m = 0; m < 4; ++m)
            p[m] = fmaxf(a0[m] + b1v, 0.f) * w2v;
        #pragma unroll
        for (int m = 0; m < 4; ++m) {
            float v = p[m];
            for (int off = 32; off > 0; off >>= 1) v += __shfl_down(v, off);
            if (lane == 0) red[w][m] = v;
        }
    }
    __syncthreads();
    if (t < ROWS4) {
        float s = b2[y];
        #pragma unroll
        for (int ww = 0; ww < 8; ++ww) s += red[ww][t];
        out[(size_t)(b0 + t) * NY + y] = s;
    }
}

extern "C" void kernel_launch(void* const* d_in, const int* in_sizes, int n_in,
                              void* d_out, int out_size, void* d_ws, size_t ws_size,
                              hipStream_t stream) {
    const float* x   = (const float*)d_in[0];
    const float* w_x = (const float*)d_in[1];
    const float* w_h = (const float*)d_in[2];
    const float* b   = (const float*)d_in[3];
    const float* W1  = (const float*)d_in[4];
    const float* b1  = (const float*)d_in[5];
    const float* W2  = (const float*)d_in[6];
    const float* b2  = (const float*)d_in[7];
    float* out = (float*)d_out;

    dim3 grid(512), block(512);
    hipLaunchKernelGGL(cwrnn_mfma9, grid, block, 0, stream,
                       x, w_x, w_h, b, W1, b1, W2, b2, out);
}